// Round 3
// baseline (45290.652 us; speedup 1.0000x reference)
//
#include <hip/hip_runtime.h>
#include <math.h>

#define BROWS  131072
#define FRAME  267
#define HDIM   512
#define LATENT 256
#define KCODES 1024

// Swizzled LDS placement for B/E tiles: 16B chunk c (8 floats, c=0..15) goes
// at float offset F(c) = 8c + 4*(c>>2); row stride 140 floats (16B aligned).
// A wave's 16 distinct chunks then start at banks
// {0,8,16,24,4,12,20,28,8,16,24,0,12,20,28,4}: every bank covered exactly 2x
// (2-way aliasing is free for wave64) vs the linear layout's 4-way conflict
// (chunks at 32B stride alias to bank groups {0,8,16,24}).
__device__ __forceinline__ int fsw16(int c) { return c * 8 + ((c >> 2) << 2); }

// ======================= fp32 tiled GEMM =======================
// C[M,N] = act(A_eff @ W + bias); W row-major [K,N]; C row-major ldc=N.
// BM=128, BN=128, BK=16, 256 threads, 8x8 micro-tile.
// Double-buffered LDS (one barrier per k-tile) + register prefetch of the
// next tile issued before the barrier (T14) + swizzled Bs.
// AKIND: 0 = plain A [M,K] (K%16==0), 1 = concat(x,c) K=534,
//        2 = concat(embedT[ind[row]], c) K=523
template<int AKIND, bool RELU, bool NVEC>
__global__ __launch_bounds__(256, 2)
void gemm_k(const float* __restrict__ A,
            const float* __restrict__ xin,
            const float* __restrict__ cin,
            const int*   __restrict__ ind,
            const float* __restrict__ embedT,
            const float* __restrict__ W,
            const float* __restrict__ bias,
            float* __restrict__ C,
            int N, int K)
{
    __shared__ __align__(16) float As[2][16][136];
    __shared__ __align__(16) float Bs[2][16][140];

    const int tid = threadIdx.x;
    const int tx = tid & 15, ty = tid >> 4;
    const int rowBase = blockIdx.y * 128;
    const int colBase = blockIdx.x * 128;

    const int arow = tid >> 1;          // 0..127: A row within tile
    const int aseg = (tid & 1) * 8;     // k sub-segment 0/8
    const int brow = tid >> 4;          // 0..15 : W row within k-tile
    const int bcol = (tid & 15) * 8;    // global col chunk (unswizzled)
    const int fb   = fsw16(tid & 15);   // swizzled LDS float offset (write+read: tx==tid&15)
    const int grow = rowBase + arow;

    int indr = 0;
    if constexpr (AKIND == 2) indr = ind[grow];

    auto loadA = [&](int kt, float av[8]) {
        const int k0 = kt << 4;
        if constexpr (AKIND == 0) {
            const float4* ap = reinterpret_cast<const float4*>(A + (size_t)grow * K + (k0 + aseg));
            float4 a0 = ap[0], a1 = ap[1];
            av[0]=a0.x; av[1]=a0.y; av[2]=a0.z; av[3]=a0.w;
            av[4]=a1.x; av[5]=a1.y; av[6]=a1.z; av[7]=a1.w;
        } else if constexpr (AKIND == 1) {
            #pragma unroll
            for (int j = 0; j < 8; ++j) {
                int k = k0 + aseg + j;
                float v = 0.f;
                if (k < FRAME)          v = xin[(size_t)grow * FRAME + k];
                else if (k < 2 * FRAME) v = cin[(size_t)grow * FRAME + (k - FRAME)];
                av[j] = v;
            }
        } else {
            int kseg = k0 + aseg;
            if (kseg + 7 < LATENT) {
                const float4* ap = reinterpret_cast<const float4*>(embedT + (size_t)indr * LATENT + kseg);
                float4 a0 = ap[0], a1 = ap[1];
                av[0]=a0.x; av[1]=a0.y; av[2]=a0.z; av[3]=a0.w;
                av[4]=a1.x; av[5]=a1.y; av[6]=a1.z; av[7]=a1.w;
            } else {
                #pragma unroll
                for (int j = 0; j < 8; ++j) {
                    int k = kseg + j;
                    float v = 0.f;
                    if (k < LATENT)              v = embedT[(size_t)indr * LATENT + k];
                    else if (k < LATENT + FRAME) v = cin[(size_t)grow * FRAME + (k - LATENT)];
                    av[j] = v;
                }
            }
        }
    };

    auto loadW = [&](int kt, float wv[8]) {
        const int kw = (kt << 4) + brow;
        if (kw < K) {
            if constexpr (NVEC) {
                const float4* wp = reinterpret_cast<const float4*>(W + (size_t)kw * N + colBase + bcol);
                float4 w0 = wp[0], w1 = wp[1];
                wv[0]=w0.x; wv[1]=w0.y; wv[2]=w0.z; wv[3]=w0.w;
                wv[4]=w1.x; wv[5]=w1.y; wv[6]=w1.z; wv[7]=w1.w;
            } else {
                #pragma unroll
                for (int j = 0; j < 8; ++j) {
                    int col = colBase + bcol + j;
                    wv[j] = (col < N) ? W[(size_t)kw * N + col] : 0.f;
                }
            }
        } else {
            #pragma unroll
            for (int j = 0; j < 8; ++j) wv[j] = 0.f;
        }
    };

    float acc[8][8];
    #pragma unroll
    for (int i = 0; i < 8; ++i)
        #pragma unroll
        for (int j = 0; j < 8; ++j) acc[i][j] = 0.f;

    float av[8], wv[8];
    loadA(0, av); loadW(0, wv);

    const int KT = (K + 15) >> 4;
    for (int kt = 0; kt < KT; ++kt) {
        const int p = kt & 1;

        // stage tile kt into buffer p (safe: barrier(kt-1) proves all waves
        // finished FMA(kt-2), the last reader of buffer p)
        #pragma unroll
        for (int j = 0; j < 8; ++j) As[p][aseg + j][arow] = av[j];
        *reinterpret_cast<float4*>(&Bs[p][brow][fb])     = make_float4(wv[0],wv[1],wv[2],wv[3]);
        *reinterpret_cast<float4*>(&Bs[p][brow][fb + 4]) = make_float4(wv[4],wv[5],wv[6],wv[7]);

        // issue next tile's global loads NOW: latency hides under the FMA loop
        float av2[8], wv2[8];
        const bool more = (kt + 1 < KT);
        if (more) { loadA(kt + 1, av2); loadW(kt + 1, wv2); }

        __syncthreads();

        #pragma unroll
        for (int k = 0; k < 16; ++k) {
            float4 a0 = *reinterpret_cast<const float4*>(&As[p][k][ty*8]);
            float4 a1 = *reinterpret_cast<const float4*>(&As[p][k][ty*8+4]);
            float4 b0 = *reinterpret_cast<const float4*>(&Bs[p][k][fb]);
            float4 b1 = *reinterpret_cast<const float4*>(&Bs[p][k][fb+4]);
            float a[8] = {a0.x,a0.y,a0.z,a0.w,a1.x,a1.y,a1.z,a1.w};
            float b[8] = {b0.x,b0.y,b0.z,b0.w,b1.x,b1.y,b1.z,b1.w};
            #pragma unroll
            for (int i = 0; i < 8; ++i)
                #pragma unroll
                for (int j = 0; j < 8; ++j)
                    acc[i][j] = fmaf(a[i], b[j], acc[i][j]);
        }

        if (more) {
            #pragma unroll
            for (int j = 0; j < 8; ++j) { av[j] = av2[j]; wv[j] = wv2[j]; }
        }
    }

    #pragma unroll
    for (int i = 0; i < 8; ++i) {
        const int row = rowBase + ty * 8 + i;
        float* crow = C + (size_t)row * N;
        if constexpr (NVEC) {
            const int col = colBase + tx * 8;
            float v[8];
            #pragma unroll
            for (int j = 0; j < 8; ++j) {
                float t = acc[i][j] + bias[col + j];
                if constexpr (RELU) t = fmaxf(t, 0.f);
                v[j] = t;
            }
            *reinterpret_cast<float4*>(crow + col)     = make_float4(v[0],v[1],v[2],v[3]);
            *reinterpret_cast<float4*>(crow + col + 4) = make_float4(v[4],v[5],v[6],v[7]);
        } else {
            #pragma unroll
            for (int j = 0; j < 8; ++j) {
                const int col = colBase + tx * 8 + j;
                if (col < N) {
                    float t = acc[i][j] + bias[col];
                    if constexpr (RELU) t = fmaxf(t, 0.f);
                    crow[col] = t;
                }
            }
        }
    }
}

// ======================= VQ argmin (v3) =======================
// Same gemm skeleton: 128 rows/block, 8 code-tiles of 128 codes, BK=16.
// Double-buffered LDS (1 barrier/phase, 128 total vs 256), register
// prefetch of the next (ct,kt) phase (hides the 8x mu re-read latency),
// swizzled Es (kills the 4-way ds_read_b128 conflict), and a shuffle-based
// cross-thread argmin (removes 17.9KB of reduction LDS -> ~36KB/block).
// score_k = ||e_k||^2 - 2 mu.e_k  (||mu||^2 cancels); tie-break lowest code.
__global__ __launch_bounds__(256, 2)
void vq_k(const float* __restrict__ mu,     // [B,256]
          const float* __restrict__ embed,  // [256,1024]
          const float* __restrict__ e2,     // [1024]
          int* __restrict__ ind,
          unsigned int* __restrict__ hist,
          float* __restrict__ lossAcc)
{
    __shared__ __align__(16) float As[2][16][136];
    __shared__ __align__(16) float Es[2][16][140];
    __shared__ float mu2p[128][2];
    __shared__ float lacc;

    const int tid = threadIdx.x;
    const int tx = tid & 15, ty = tid >> 4;
    const int rowBase = blockIdx.x * 128;

    const int arow = tid >> 1;          // 0..127
    const int aseg = (tid & 1) * 8;     // 0/8
    const int brow = tid >> 4;          // 0..15 (k within tile)
    const int fb   = fsw16(tx);         // swizzled LDS float offset

    if (tid == 0) lacc = 0.f;

    auto loadPhase = [&](int phase, float av[8], float ev[8]) {
        const int ct = phase >> 4, kt = phase & 15;
        const int k0 = kt << 4;
        const float4* ap = reinterpret_cast<const float4*>(
            mu + (size_t)(rowBase + arow) * LATENT + (k0 + aseg));
        float4 a0 = ap[0], a1 = ap[1];
        av[0]=a0.x; av[1]=a0.y; av[2]=a0.z; av[3]=a0.w;
        av[4]=a1.x; av[5]=a1.y; av[6]=a1.z; av[7]=a1.w;
        const float* eb = embed + (size_t)(k0 + brow) * KCODES + ct * 128 + tx * 8;
        float4 e0 = *reinterpret_cast<const float4*>(eb);
        float4 e1 = *reinterpret_cast<const float4*>(eb + 4);
        ev[0]=e0.x; ev[1]=e0.y; ev[2]=e0.z; ev[3]=e0.w;
        ev[4]=e1.x; ev[5]=e1.y; ev[6]=e1.z; ev[7]=e1.w;
    };

    float best[8]; int bidx[8];
    #pragma unroll
    for (int i = 0; i < 8; ++i) { best[i] = 3.4e38f; bidx[i] = 0; }
    float mu2 = 0.f;

    float av[8], ev[8];
    loadPhase(0, av, ev);

    int phase = 0;
    for (int ct = 0; ct < 8; ++ct) {
        float acc[8][8];
        #pragma unroll
        for (int i = 0; i < 8; ++i)
            #pragma unroll
            for (int j = 0; j < 8; ++j) acc[i][j] = 0.f;

        for (int kt = 0; kt < 16; ++kt, ++phase) {
            const int p = phase & 1;

            #pragma unroll
            for (int j = 0; j < 8; ++j) As[p][aseg + j][arow] = av[j];
            *reinterpret_cast<float4*>(&Es[p][brow][fb])     = make_float4(ev[0],ev[1],ev[2],ev[3]);
            *reinterpret_cast<float4*>(&Es[p][brow][fb + 4]) = make_float4(ev[4],ev[5],ev[6],ev[7]);
            if (ct == 0) {
                #pragma unroll
                for (int j = 0; j < 8; ++j) mu2 = fmaf(av[j], av[j], mu2);
            }

            float av2[8], ev2[8];
            const bool more = (phase + 1 < 128);
            if (more) loadPhase(phase + 1, av2, ev2);

            __syncthreads();

            #pragma unroll
            for (int k = 0; k < 16; ++k) {
                float4 A0 = *reinterpret_cast<const float4*>(&As[p][k][ty*8]);
                float4 A1 = *reinterpret_cast<const float4*>(&As[p][k][ty*8+4]);
                float4 B0 = *reinterpret_cast<const float4*>(&Es[p][k][fb]);
                float4 B1 = *reinterpret_cast<const float4*>(&Es[p][k][fb+4]);
                float a[8] = {A0.x,A0.y,A0.z,A0.w,A1.x,A1.y,A1.z,A1.w};
                float b[8] = {B0.x,B0.y,B0.z,B0.w,B1.x,B1.y,B1.z,B1.w};
                #pragma unroll
                for (int i = 0; i < 8; ++i)
                    #pragma unroll
                    for (int j = 0; j < 8; ++j)
                        acc[i][j] = fmaf(a[i], b[j], acc[i][j]);
            }

            if (more) {
                #pragma unroll
                for (int j = 0; j < 8; ++j) { av[j] = av2[j]; ev[j] = ev2[j]; }
            }
        }
        if (ct == 0) mu2p[arow][tid & 1] = mu2;

        // fused argmin epilogue (registers only; e2 is 4KB, L2-hot)
        float4 ea = *reinterpret_cast<const float4*>(e2 + ct * 128 + tx * 8);
        float4 eb = *reinterpret_cast<const float4*>(e2 + ct * 128 + tx * 8 + 4);
        float e2v[8] = {ea.x,ea.y,ea.z,ea.w,eb.x,eb.y,eb.z,eb.w};
        #pragma unroll
        for (int j = 0; j < 8; ++j) {
            const int code = ct * 128 + tx * 8 + j;
            #pragma unroll
            for (int i = 0; i < 8; ++i) {
                float s = fmaf(-2.f, acc[i][j], e2v[j]);
                if (s < best[i]) { best[i] = s; bidx[i] = code; }
            }
        }
    }

    // ---- cross-thread reduction via shuffles over the 16-lane tx group ----
    #pragma unroll
    for (int m = 1; m < 16; m <<= 1) {
        #pragma unroll
        for (int i = 0; i < 8; ++i) {
            float v  = __shfl_xor(best[i], m);
            int   vi = __shfl_xor(bidx[i], m);
            if (v < best[i] || (v == best[i] && vi < bidx[i])) { best[i] = v; bidx[i] = vi; }
        }
    }

    __syncthreads();   // mu2p + lacc visibility
    if (tx == 0) {
        float ls = 0.f;
        #pragma unroll
        for (int i = 0; i < 8; ++i) {
            const int r = ty * 8 + i;
            ind[rowBase + r] = bidx[i];
            atomicAdd(&hist[bidx[i]], 1u);
            ls += mu2p[r][0] + mu2p[r][1] + best[i];   // ||mu - e_best||^2
        }
        atomicAdd(&lacc, ls);
    }
    __syncthreads();
    if (tid == 0) atomicAdd(lossAcc, lacc);            // one atomic per block
}

// ======================= small helpers =======================
__global__ void e2_k(const float* __restrict__ embed, float* __restrict__ e2)
{
    int n = blockIdx.x * 256 + threadIdx.x;   // 1024 total
    float s = 0.f;
    for (int d = 0; d < LATENT; ++d) {
        float v = embed[(size_t)d * KCODES + n];
        s = fmaf(v, v, s);
    }
    e2[n] = s;
}

__global__ void tr_k(const float* __restrict__ embed, float* __restrict__ embedT)
{
    __shared__ float t[32][33];
    const int tx = threadIdx.x & 31, ty = threadIdx.x >> 5;  // ty 0..7
    #pragma unroll
    for (int i = 0; i < 4; ++i) {
        int d = blockIdx.y * 32 + ty + i * 8;
        t[ty + i * 8][tx] = embed[(size_t)d * KCODES + blockIdx.x * 32 + tx];
    }
    __syncthreads();
    #pragma unroll
    for (int i = 0; i < 4; ++i) {
        int n = blockIdx.x * 32 + ty + i * 8;
        embedT[(size_t)n * LATENT + blockIdx.y * 32 + tx] = t[tx][ty + i * 8];
    }
}

__global__ void fin_k(const unsigned int* __restrict__ hist,
                      const float* __restrict__ lossAcc,
                      float* __restrict__ out2)
{
    __shared__ double sh[256];
    const int tid = threadIdx.x;
    double s = 0.0;
    for (int i = tid; i < KCODES; i += 256) {
        double p = (double)hist[i] / (double)BROWS;
        s += p * log(p + 1e-10);
    }
    sh[tid] = s; __syncthreads();
    for (int off = 128; off > 0; off >>= 1) {
        if (tid < off) sh[tid] += sh[tid + off];
        __syncthreads();
    }
    if (tid == 0) {
        out2[0] = lossAcc[0] / ((float)BROWS * (float)LATENT);   // loss
        out2[1] = (float)exp(-sh[0]);                            // perplexity
    }
}

// ======================= launch =======================
extern "C" void kernel_launch(void* const* d_in, const int* in_sizes, int n_in,
                              void* d_out, int out_size, void* d_ws, size_t ws_size,
                              hipStream_t stream)
{
    const float* x    = (const float*)d_in[0];
    const float* c    = (const float*)d_in[1];
    const float* W1   = (const float*)d_in[2];  const float* b1  = (const float*)d_in[3];
    const float* W2   = (const float*)d_in[4];  const float* b2  = (const float*)d_in[5];
    const float* W3   = (const float*)d_in[6];  const float* b3  = (const float*)d_in[7];
    const float* Wmu  = (const float*)d_in[8];  const float* bmu = (const float*)d_in[9];
    const float* W4   = (const float*)d_in[10]; const float* b4  = (const float*)d_in[11];
    const float* W5   = (const float*)d_in[12]; const float* b5  = (const float*)d_in[13];
    const float* W6   = (const float*)d_in[14]; const float* b6  = (const float*)d_in[15];
    const float* Wo   = (const float*)d_in[16]; const float* bo  = (const float*)d_in[17];
    const float* embed= (const float*)d_in[18];

    float* out = (float*)d_out;

    char* ws = (char*)d_ws;
    float* buf0 = (float*)ws;  ws += (size_t)BROWS * HDIM * sizeof(float);
    float* buf1 = (float*)ws;  ws += (size_t)BROWS * HDIM * sizeof(float);
    int*   ind  = (int*)ws;    ws += (size_t)BROWS * sizeof(int);
    float* embedT = (float*)ws; ws += (size_t)KCODES * LATENT * sizeof(float);
    float* e2   = (float*)ws;  ws += KCODES * sizeof(float);
    unsigned int* hist = (unsigned int*)ws; ws += KCODES * sizeof(unsigned int);
    float* lossAcc = (float*)ws; ws += 16;

    hipMemsetAsync(hist, 0, KCODES * sizeof(unsigned int) + 16, stream);
    e2_k<<<dim3(4), dim3(256), 0, stream>>>(embed, e2);
    tr_k<<<dim3(32, 8), dim3(256), 0, stream>>>(embed, embedT);

    const dim3 blk(256);
    const dim3 g512(4, BROWS / 128);
    const dim3 g256(2, BROWS / 128);
    const dim3 g267(3, BROWS / 128);

    // ---- encoder (fp32 to protect argmin) ----
    gemm_k<1, true,  true ><<<g512, blk, 0, stream>>>(nullptr, x, c, nullptr, nullptr, W1,  b1,  buf0, 512, 534);
    gemm_k<0, true,  true ><<<g512, blk, 0, stream>>>(buf0, nullptr, nullptr, nullptr, nullptr, W2,  b2,  buf1, 512, 512);
    gemm_k<0, true,  true ><<<g512, blk, 0, stream>>>(buf1, nullptr, nullptr, nullptr, nullptr, W3,  b3,  buf0, 512, 512);
    gemm_k<0, false, true ><<<g256, blk, 0, stream>>>(buf0, nullptr, nullptr, nullptr, nullptr, Wmu, bmu, buf1, 256, 512);

    // ---- vector quantizer (mu = buf1) ----
    vq_k<<<dim3(BROWS / 128), blk, 0, stream>>>(buf1, embed, e2, ind, hist, lossAcc);

    // ---- decoder ----
    gemm_k<2, true,  true ><<<g512, blk, 0, stream>>>(nullptr, nullptr, c, ind, embedT, W4, b4, buf0, 512, 523);
    gemm_k<0, true,  true ><<<g512, blk, 0, stream>>>(buf0, nullptr, nullptr, nullptr, nullptr, W5, b5, buf1, 512, 512);
    gemm_k<0, true,  true ><<<g512, blk, 0, stream>>>(buf1, nullptr, nullptr, nullptr, nullptr, W6, b6, buf0, 512, 512);
    gemm_k<0, false, false><<<g267, blk, 0, stream>>>(buf0, nullptr, nullptr, nullptr, nullptr, Wo, bo, out, 267, 512);

    // ---- loss + perplexity ----
    fin_k<<<dim3(1), dim3(256), 0, stream>>>(hist, lossAcc, out + (size_t)BROWS * FRAME);
}

// Round 4
// 8664.615 us; speedup vs baseline: 5.2271x; 5.2271x over previous
//
#include <hip/hip_runtime.h>
#include <math.h>

#define BROWS  131072
#define FRAME  267
#define HDIM   512
#define LATENT 256
#define KCODES 1024

// Swizzled LDS placement for B/E tiles: 16B chunk c (8 floats, c=0..15) goes
// at float offset F(c) = 8c + 4*(c>>2); row stride 140 floats (16B aligned).
// A wave's 16 distinct chunks then cover every bank exactly 2x (2-way is free
// on wave64) vs the linear layout's 4-way conflict.
__device__ __forceinline__ int fsw16(int c) { return c * 8 + ((c >> 2) << 2); }

// 8 floats in two float4s. Passed/returned BY VALUE so SROA keeps it in
// registers (rule #20: array-out params become scratch allocas).
struct F8 { float4 lo, hi; };

// ======================= fp32 tiled GEMM =======================
// C[M,N] = act(A_eff @ W + bias); W row-major [K,N]; C row-major ldc=N.
// BM=128, BN=128, BK=16, 256 threads, 8x8 micro-tile.
// Double-buffered LDS (one barrier per k-tile) + register prefetch of the
// next tile (clamped index: no divergent guard, no conditional copies).
// AKIND: 0 = plain A [M,K] (K%16==0), 1 = concat(x,c) K=534,
//        2 = concat(embedT[ind[row]], c) K=523
template<int AKIND, bool RELU, bool NVEC>
__global__ __launch_bounds__(256, 2)
void gemm_k(const float* __restrict__ A,
            const float* __restrict__ xin,
            const float* __restrict__ cin,
            const int*   __restrict__ ind,
            const float* __restrict__ embedT,
            const float* __restrict__ W,
            const float* __restrict__ bias,
            float* __restrict__ C,
            int N, int K)
{
    __shared__ __align__(16) float As[2][16][136];
    __shared__ __align__(16) float Bs[2][16][140];

    const int tid = threadIdx.x;
    const int tx = tid & 15, ty = tid >> 4;
    const int rowBase = blockIdx.y * 128;
    const int colBase = blockIdx.x * 128;

    const int arow = tid >> 1;          // 0..127: A row within tile
    const int aseg = (tid & 1) * 8;     // k sub-segment 0/8
    const int brow = tid >> 4;          // 0..15 : W row within k-tile
    const int bcol = (tid & 15) * 8;    // global col chunk (unswizzled)
    const int fb   = fsw16(tid & 15);   // swizzled LDS float offset
    const int grow = rowBase + arow;

    int indr = 0;
    if constexpr (AKIND == 2) indr = ind[grow];

    auto loadA = [&](int kt) -> F8 {
        const int k0 = kt << 4;
        F8 r;
        if constexpr (AKIND == 0) {
            const float4* ap = reinterpret_cast<const float4*>(A + (size_t)grow * K + (k0 + aseg));
            r.lo = ap[0]; r.hi = ap[1];
        } else if constexpr (AKIND == 1) {
            float t[8];
            #pragma unroll
            for (int j = 0; j < 8; ++j) {
                int k = k0 + aseg + j;
                float v = 0.f;
                if (k < FRAME)          v = xin[(size_t)grow * FRAME + k];
                else if (k < 2 * FRAME) v = cin[(size_t)grow * FRAME + (k - FRAME)];
                t[j] = v;
            }
            r.lo = make_float4(t[0], t[1], t[2], t[3]);
            r.hi = make_float4(t[4], t[5], t[6], t[7]);
        } else {
            const int kseg = k0 + aseg;
            if (kseg + 7 < LATENT) {
                const float4* ap = reinterpret_cast<const float4*>(embedT + (size_t)indr * LATENT + kseg);
                r.lo = ap[0]; r.hi = ap[1];
            } else {
                float t[8];
                #pragma unroll
                for (int j = 0; j < 8; ++j) {
                    int k = kseg + j;
                    float v = 0.f;
                    if (k < LATENT)              v = embedT[(size_t)indr * LATENT + k];
                    else if (k < LATENT + FRAME) v = cin[(size_t)grow * FRAME + (k - LATENT)];
                    t[j] = v;
                }
                r.lo = make_float4(t[0], t[1], t[2], t[3]);
                r.hi = make_float4(t[4], t[5], t[6], t[7]);
            }
        }
        return r;
    };

    auto loadW = [&](int kt) -> F8 {
        const int kw = (kt << 4) + brow;
        F8 r;
        if (kw < K) {
            if constexpr (NVEC) {
                const float4* wp = reinterpret_cast<const float4*>(W + (size_t)kw * N + colBase + bcol);
                r.lo = wp[0]; r.hi = wp[1];
            } else {
                float t[8];
                #pragma unroll
                for (int j = 0; j < 8; ++j) {
                    int col = colBase + bcol + j;
                    t[j] = (col < N) ? W[(size_t)kw * N + col] : 0.f;
                }
                r.lo = make_float4(t[0], t[1], t[2], t[3]);
                r.hi = make_float4(t[4], t[5], t[6], t[7]);
            }
        } else {
            r.lo = make_float4(0.f, 0.f, 0.f, 0.f);
            r.hi = make_float4(0.f, 0.f, 0.f, 0.f);
        }
        return r;
    };

    float acc[8][8];
    #pragma unroll
    for (int i = 0; i < 8; ++i)
        #pragma unroll
        for (int j = 0; j < 8; ++j) acc[i][j] = 0.f;

    F8 aC = loadA(0), wC = loadW(0);

    const int KT = (K + 15) >> 4;
    for (int kt = 0; kt < KT; ++kt) {
        const int p = kt & 1;

        // stage tile kt into buffer p (safe: barrier(kt-1) proves all waves
        // finished FMA(kt-2), the last reader of buffer p)
        As[p][aseg + 0][arow] = aC.lo.x; As[p][aseg + 1][arow] = aC.lo.y;
        As[p][aseg + 2][arow] = aC.lo.z; As[p][aseg + 3][arow] = aC.lo.w;
        As[p][aseg + 4][arow] = aC.hi.x; As[p][aseg + 5][arow] = aC.hi.y;
        As[p][aseg + 6][arow] = aC.hi.z; As[p][aseg + 7][arow] = aC.hi.w;
        *reinterpret_cast<float4*>(&Bs[p][brow][fb])     = wC.lo;
        *reinterpret_cast<float4*>(&Bs[p][brow][fb + 4]) = wC.hi;

        // prefetch next tile (clamped: last iter redundantly reloads tile kt)
        const int ktn = (kt + 1 < KT) ? (kt + 1) : kt;
        F8 aN = loadA(ktn), wN = loadW(ktn);

        __syncthreads();

        #pragma unroll
        for (int k = 0; k < 16; ++k) {
            float4 a0 = *reinterpret_cast<const float4*>(&As[p][k][ty*8]);
            float4 a1 = *reinterpret_cast<const float4*>(&As[p][k][ty*8+4]);
            float4 b0 = *reinterpret_cast<const float4*>(&Bs[p][k][fb]);
            float4 b1 = *reinterpret_cast<const float4*>(&Bs[p][k][fb+4]);
            float a[8] = {a0.x,a0.y,a0.z,a0.w,a1.x,a1.y,a1.z,a1.w};
            float b[8] = {b0.x,b0.y,b0.z,b0.w,b1.x,b1.y,b1.z,b1.w};
            #pragma unroll
            for (int i = 0; i < 8; ++i)
                #pragma unroll
                for (int j = 0; j < 8; ++j)
                    acc[i][j] = fmaf(a[i], b[j], acc[i][j]);
        }

        aC = aN; wC = wN;
    }

    #pragma unroll
    for (int i = 0; i < 8; ++i) {
        const int row = rowBase + ty * 8 + i;
        float* crow = C + (size_t)row * N;
        if constexpr (NVEC) {
            const int col = colBase + tx * 8;
            float v[8];
            #pragma unroll
            for (int j = 0; j < 8; ++j) {
                float t = acc[i][j] + bias[col + j];
                if constexpr (RELU) t = fmaxf(t, 0.f);
                v[j] = t;
            }
            *reinterpret_cast<float4*>(crow + col)     = make_float4(v[0],v[1],v[2],v[3]);
            *reinterpret_cast<float4*>(crow + col + 4) = make_float4(v[4],v[5],v[6],v[7]);
        } else {
            #pragma unroll
            for (int j = 0; j < 8; ++j) {
                const int col = colBase + tx * 8 + j;
                if (col < N) {
                    float t = acc[i][j] + bias[col];
                    if constexpr (RELU) t = fmaxf(t, 0.f);
                    crow[col] = t;
                }
            }
        }
    }
}

// ======================= VQ argmin (v4) =======================
// gemm skeleton: 128 rows/block, 8 code-tiles of 128 codes, BK=16.
// Double-buffered LDS (1 barrier/phase), register prefetch via F8-by-value
// (spill-free), swizzled Es, shuffle-based cross-thread argmin.
// score_k = ||e_k||^2 - 2 mu.e_k  (||mu||^2 cancels); tie-break lowest code.
__global__ __launch_bounds__(256, 2)
void vq_k(const float* __restrict__ mu,     // [B,256]
          const float* __restrict__ embed,  // [256,1024]
          const float* __restrict__ e2,     // [1024]
          int* __restrict__ ind,
          unsigned int* __restrict__ hist,
          float* __restrict__ lossAcc)
{
    __shared__ __align__(16) float As[2][16][136];
    __shared__ __align__(16) float Es[2][16][140];
    __shared__ float mu2p[128][2];
    __shared__ float lacc;

    const int tid = threadIdx.x;
    const int tx = tid & 15, ty = tid >> 4;
    const int rowBase = blockIdx.x * 128;

    const int arow = tid >> 1;          // 0..127
    const int aseg = (tid & 1) * 8;     // 0/8
    const int brow = tid >> 4;          // 0..15 (k within tile)
    const int fb   = fsw16(tx);         // swizzled LDS float offset

    if (tid == 0) lacc = 0.f;

    auto loadMu = [&](int ph) -> F8 {
        const int k0 = (ph & 15) << 4;
        const float4* ap = reinterpret_cast<const float4*>(
            mu + (size_t)(rowBase + arow) * LATENT + (k0 + aseg));
        F8 r; r.lo = ap[0]; r.hi = ap[1]; return r;
    };
    auto loadE = [&](int ph) -> F8 {
        const int ct = ph >> 4, k0 = (ph & 15) << 4;
        const float* eb = embed + (size_t)(k0 + brow) * KCODES + ct * 128 + tx * 8;
        F8 r;
        r.lo = *reinterpret_cast<const float4*>(eb);
        r.hi = *reinterpret_cast<const float4*>(eb + 4);
        return r;
    };

    float best[8]; int bidx[8];
    #pragma unroll
    for (int i = 0; i < 8; ++i) { best[i] = 3.4e38f; bidx[i] = 0; }
    float mu2 = 0.f;

    F8 aC = loadMu(0), eC = loadE(0);

    int phase = 0;
    for (int ct = 0; ct < 8; ++ct) {
        float acc[8][8];
        #pragma unroll
        for (int i = 0; i < 8; ++i)
            #pragma unroll
            for (int j = 0; j < 8; ++j) acc[i][j] = 0.f;

        for (int kt = 0; kt < 16; ++kt, ++phase) {
            const int p = phase & 1;

            As[p][aseg + 0][arow] = aC.lo.x; As[p][aseg + 1][arow] = aC.lo.y;
            As[p][aseg + 2][arow] = aC.lo.z; As[p][aseg + 3][arow] = aC.lo.w;
            As[p][aseg + 4][arow] = aC.hi.x; As[p][aseg + 5][arow] = aC.hi.y;
            As[p][aseg + 6][arow] = aC.hi.z; As[p][aseg + 7][arow] = aC.hi.w;
            *reinterpret_cast<float4*>(&Es[p][brow][fb])     = eC.lo;
            *reinterpret_cast<float4*>(&Es[p][brow][fb + 4]) = eC.hi;
            if (ct == 0) {
                mu2 += aC.lo.x*aC.lo.x + aC.lo.y*aC.lo.y + aC.lo.z*aC.lo.z + aC.lo.w*aC.lo.w
                     + aC.hi.x*aC.hi.x + aC.hi.y*aC.hi.y + aC.hi.z*aC.hi.z + aC.hi.w*aC.hi.w;
            }

            // prefetch next phase (clamped: last phase reloads itself)
            const int phn = (phase + 1 < 128) ? (phase + 1) : phase;
            F8 aN = loadMu(phn), eN = loadE(phn);

            __syncthreads();

            #pragma unroll
            for (int k = 0; k < 16; ++k) {
                float4 A0 = *reinterpret_cast<const float4*>(&As[p][k][ty*8]);
                float4 A1 = *reinterpret_cast<const float4*>(&As[p][k][ty*8+4]);
                float4 B0 = *reinterpret_cast<const float4*>(&Es[p][k][fb]);
                float4 B1 = *reinterpret_cast<const float4*>(&Es[p][k][fb+4]);
                float a[8] = {A0.x,A0.y,A0.z,A0.w,A1.x,A1.y,A1.z,A1.w};
                float b[8] = {B0.x,B0.y,B0.z,B0.w,B1.x,B1.y,B1.z,B1.w};
                #pragma unroll
                for (int i = 0; i < 8; ++i)
                    #pragma unroll
                    for (int j = 0; j < 8; ++j)
                        acc[i][j] = fmaf(a[i], b[j], acc[i][j]);
            }

            aC = aN; eC = eN;
        }
        if (ct == 0) mu2p[arow][tid & 1] = mu2;

        // fused argmin epilogue (registers only; e2 is 4KB, L2-hot)
        float4 ea = *reinterpret_cast<const float4*>(e2 + ct * 128 + tx * 8);
        float4 eb = *reinterpret_cast<const float4*>(e2 + ct * 128 + tx * 8 + 4);
        float e2v[8] = {ea.x,ea.y,ea.z,ea.w,eb.x,eb.y,eb.z,eb.w};
        #pragma unroll
        for (int j = 0; j < 8; ++j) {
            const int code = ct * 128 + tx * 8 + j;
            #pragma unroll
            for (int i = 0; i < 8; ++i) {
                float s = fmaf(-2.f, acc[i][j], e2v[j]);
                if (s < best[i]) { best[i] = s; bidx[i] = code; }
            }
        }
    }

    // ---- cross-thread reduction via shuffles over the 16-lane tx group ----
    #pragma unroll
    for (int m = 1; m < 16; m <<= 1) {
        #pragma unroll
        for (int i = 0; i < 8; ++i) {
            float v  = __shfl_xor(best[i], m);
            int   vi = __shfl_xor(bidx[i], m);
            if (v < best[i] || (v == best[i] && vi < bidx[i])) { best[i] = v; bidx[i] = vi; }
        }
    }

    __syncthreads();   // mu2p + lacc visibility
    if (tx == 0) {
        float ls = 0.f;
        #pragma unroll
        for (int i = 0; i < 8; ++i) {
            const int r = ty * 8 + i;
            ind[rowBase + r] = bidx[i];
            atomicAdd(&hist[bidx[i]], 1u);
            ls += mu2p[r][0] + mu2p[r][1] + best[i];   // ||mu - e_best||^2
        }
        atomicAdd(&lacc, ls);
    }
    __syncthreads();
    if (tid == 0) atomicAdd(lossAcc, lacc);            // one atomic per block
}

// ======================= small helpers =======================
__global__ void e2_k(const float* __restrict__ embed, float* __restrict__ e2)
{
    int n = blockIdx.x * 256 + threadIdx.x;   // 1024 total
    float s = 0.f;
    for (int d = 0; d < LATENT; ++d) {
        float v = embed[(size_t)d * KCODES + n];
        s = fmaf(v, v, s);
    }
    e2[n] = s;
}

__global__ void tr_k(const float* __restrict__ embed, float* __restrict__ embedT)
{
    __shared__ float t[32][33];
    const int tx = threadIdx.x & 31, ty = threadIdx.x >> 5;  // ty 0..7
    #pragma unroll
    for (int i = 0; i < 4; ++i) {
        int d = blockIdx.y * 32 + ty + i * 8;
        t[ty + i * 8][tx] = embed[(size_t)d * KCODES + blockIdx.x * 32 + tx];
    }
    __syncthreads();
    #pragma unroll
    for (int i = 0; i < 4; ++i) {
        int n = blockIdx.x * 32 + ty + i * 8;
        embedT[(size_t)n * LATENT + blockIdx.y * 32 + tx] = t[tx][ty + i * 8];
    }
}

__global__ void fin_k(const unsigned int* __restrict__ hist,
                      const float* __restrict__ lossAcc,
                      float* __restrict__ out2)
{
    __shared__ double sh[256];
    const int tid = threadIdx.x;
    double s = 0.0;
    for (int i = tid; i < KCODES; i += 256) {
        double p = (double)hist[i] / (double)BROWS;
        s += p * log(p + 1e-10);
    }
    sh[tid] = s; __syncthreads();
    for (int off = 128; off > 0; off >>= 1) {
        if (tid < off) sh[tid] += sh[tid + off];
        __syncthreads();
    }
    if (tid == 0) {
        out2[0] = lossAcc[0] / ((float)BROWS * (float)LATENT);   // loss
        out2[1] = (float)exp(-sh[0]);                            // perplexity
    }
}

// ======================= launch =======================
extern "C" void kernel_launch(void* const* d_in, const int* in_sizes, int n_in,
                              void* d_out, int out_size, void* d_ws, size_t ws_size,
                              hipStream_t stream)
{
    const float* x    = (const float*)d_in[0];
    const float* c    = (const float*)d_in[1];
    const float* W1   = (const float*)d_in[2];  const float* b1  = (const float*)d_in[3];
    const float* W2   = (const float*)d_in[4];  const float* b2  = (const float*)d_in[5];
    const float* W3   = (const float*)d_in[6];  const float* b3  = (const float*)d_in[7];
    const float* Wmu  = (const float*)d_in[8];  const float* bmu = (const float*)d_in[9];
    const float* W4   = (const float*)d_in[10]; const float* b4  = (const float*)d_in[11];
    const float* W5   = (const float*)d_in[12]; const float* b5  = (const float*)d_in[13];
    const float* W6   = (const float*)d_in[14]; const float* b6  = (const float*)d_in[15];
    const float* Wo   = (const float*)d_in[16]; const float* bo  = (const float*)d_in[17];
    const float* embed= (const float*)d_in[18];

    float* out = (float*)d_out;

    char* ws = (char*)d_ws;
    float* buf0 = (float*)ws;  ws += (size_t)BROWS * HDIM * sizeof(float);
    float* buf1 = (float*)ws;  ws += (size_t)BROWS * HDIM * sizeof(float);
    int*   ind  = (int*)ws;    ws += (size_t)BROWS * sizeof(int);
    float* embedT = (float*)ws; ws += (size_t)KCODES * LATENT * sizeof(float);
    float* e2   = (float*)ws;  ws += KCODES * sizeof(float);
    unsigned int* hist = (unsigned int*)ws; ws += KCODES * sizeof(unsigned int);
    float* lossAcc = (float*)ws; ws += 16;

    hipMemsetAsync(hist, 0, KCODES * sizeof(unsigned int) + 16, stream);
    e2_k<<<dim3(4), dim3(256), 0, stream>>>(embed, e2);
    tr_k<<<dim3(32, 8), dim3(256), 0, stream>>>(embed, embedT);

    const dim3 blk(256);
    const dim3 g512(4, BROWS / 128);
    const dim3 g256(2, BROWS / 128);
    const dim3 g267(3, BROWS / 128);

    // ---- encoder (fp32 to protect argmin) ----
    gemm_k<1, true,  true ><<<g512, blk, 0, stream>>>(nullptr, x, c, nullptr, nullptr, W1,  b1,  buf0, 512, 534);
    gemm_k<0, true,  true ><<<g512, blk, 0, stream>>>(buf0, nullptr, nullptr, nullptr, nullptr, W2,  b2,  buf1, 512, 512);
    gemm_k<0, true,  true ><<<g512, blk, 0, stream>>>(buf1, nullptr, nullptr, nullptr, nullptr, W3,  b3,  buf0, 512, 512);
    gemm_k<0, false, true ><<<g256, blk, 0, stream>>>(buf0, nullptr, nullptr, nullptr, nullptr, Wmu, bmu, buf1, 256, 512);

    // ---- vector quantizer (mu = buf1) ----
    vq_k<<<dim3(BROWS / 128), blk, 0, stream>>>(buf1, embed, e2, ind, hist, lossAcc);

    // ---- decoder ----
    gemm_k<2, true,  true ><<<g512, blk, 0, stream>>>(nullptr, nullptr, c, ind, embedT, W4, b4, buf0, 512, 523);
    gemm_k<0, true,  true ><<<g512, blk, 0, stream>>>(buf0, nullptr, nullptr, nullptr, nullptr, W5, b5, buf1, 512, 512);
    gemm_k<0, true,  true ><<<g512, blk, 0, stream>>>(buf1, nullptr, nullptr, nullptr, nullptr, W6, b6, buf0, 512, 512);
    gemm_k<0, false, false><<<g267, blk, 0, stream>>>(buf0, nullptr, nullptr, nullptr, nullptr, Wo, bo, out, 267, 512);

    // ---- loss + perplexity ----
    fin_k<<<dim3(1), dim3(256), 0, stream>>>(hist, lossAcc, out + (size_t)BROWS * FRAME);
}